// Round 4
// baseline (191.351 us; speedup 1.0000x reference)
//
#include <hip/hip_runtime.h>

#define BATCH 4
#define HH 128
#define WW 128
#define CC 64
#define TH 8
#define TW 8
#define HALO 12
#define HPOS 144            // 12*12 halo positions
#define ROWDW 32            // 64 ch bf16 = 128 B = 32 dwords
#define KVDW (HPOS*ROWDW)   // dwords per buffer (4608)

__device__ __forceinline__ unsigned pack2bf(float a, float b){
  unsigned ua = __float_as_uint(a), ub = __float_as_uint(b);
  ua = (ua + 0x7fffu + ((ua>>16)&1u)) >> 16;            // RTN
  ub = (ub + 0x7fffu + ((ub>>16)&1u)) >> 16;
  return ua | (ub<<16);
}

template<int CTRL>
__device__ __forceinline__ float dpp_addstep(float x){
  int p = __builtin_amdgcn_update_dpp(0, __float_as_int(x), CTRL, 0xf, 0xf, true);
  return x + __int_as_float(p);
}
// sum across 8 consecutive lanes (groups aligned to lane&~7) — pure VALU/DPP
__device__ __forceinline__ float reduce8(float x){
  x = dpp_addstep<0xB1>(x);    // quad_perm [1,0,3,2] : xor 1
  x = dpp_addstep<0x4E>(x);    // quad_perm [2,3,0,1] : xor 2
  x = dpp_addstep<0x141>(x);   // row_half_mirror     : combine the two quads
  return x;
}

__global__ __launch_bounds__(256, 4) void local_attn_kernel(
    const float* __restrict__ main_,
    const float* __restrict__ main_value,
    const float* __restrict__ ref,
    const float* __restrict__ ref_value,
    float* __restrict__ out)
{
    __shared__ unsigned kv[2*KVDW];     // K halo then V halo, bf16x2, 36864 B

    const int t   = threadIdx.x;
    const int nwg = BATCH*16*16;        // 1024, divisible by 8 -> bijective swizzle
    const int blk = (blockIdx.x & 7) * (nwg>>3) + (blockIdx.x >> 3);
    const int bx  = blk & 15;
    const int by  = (blk>>4) & 15;
    const int b   = blk >> 8;

    const int lane = t & 63;
    const int wave = t >> 6;
    const int cg8  = lane & 7;          // channel slot: ch [cg8*8, cg8*8+8)
    const int lx   = lane >> 3;         // 0..7 tile column
    const int ly0  = wave*2;            // this thread owns pixels (ly0,lx) and (ly0+1,lx)

    const int gx  = bx*TW + lx;
    const int gy0 = by*TH + ly0;

    const size_t img  = (size_t)b*HH*WW*CC;
    const size_t off0 = img + ((size_t)gy0*WW + gx)*CC + cg8*8;
    const size_t off1 = off0 + (size_t)WW*CC;

    // ---- q loads first (latency hides under staging) ----
    float4 qa0 = *(const float4*)(main_+off0), qb0 = *(const float4*)(main_+off0+4);
    float4 qa1 = *(const float4*)(main_+off1), qb1 = *(const float4*)(main_+off1+4);

    const int y0 = by*TH - 2, x0 = bx*TW - 2;

    // ---- stage K and V halos as bf16 (zero-fill OOB) ----
    #pragma unroll
    for (int half = 0; half < 2; ++half) {
        const float* src = half ? ref_value : ref;
        unsigned* dst = kv + half*KVDW;
        #pragma unroll
        for (int it = 0; it < 5; ++it) {
            int u = t + (it<<8);
            if (u < HPOS*8) {
                int pos = u >> 3, c8 = u & 7;
                int hy = pos/12, hx = pos - hy*12;
                int yy = y0+hy, xx = x0+hx;
                float4 a = make_float4(0.f,0.f,0.f,0.f);
                float4 c = make_float4(0.f,0.f,0.f,0.f);
                if ((unsigned)yy < HH && (unsigned)xx < WW) {
                    const float* g = src + img + ((size_t)yy*WW+xx)*CC + c8*8;
                    a = ((const float4*)g)[0];
                    c = ((const float4*)g)[1];
                }
                uint4 w;
                w.x = pack2bf(a.x,a.y); w.y = pack2bf(a.z,a.w);
                w.z = pack2bf(c.x,c.y); w.w = pack2bf(c.z,c.w);
                *(uint4*)(dst + pos*ROWDW + c8*4) = w;
            }
        }
    }

    __syncthreads();    // the ONLY barrier

    // ---- self-value loads issued here: land during logits/agg ----
    float4 va0 = *(const float4*)(main_value+off0), vb0 = *(const float4*)(main_value+off0+4);
    float4 va1 = *(const float4*)(main_value+off1), vb1 = *(const float4*)(main_value+off1+4);

    float q0[8] = {qa0.x,qa0.y,qa0.z,qa0.w,qb0.x,qb0.y,qb0.z,qb0.w};
    float q1[8] = {qa1.x,qa1.y,qa1.z,qa1.w,qb1.x,qb1.y,qb1.z,qb1.w};

    // ---- logits: 6 halo rows x 5 cols serve both pixels ----
    float p0[26], p1[26];
    const unsigned* KB = kv;
    #pragma unroll
    for (int di = 0; di < 6; ++di) {
        #pragma unroll
        for (int dj = 0; dj < 5; ++dj) {
            const int pos = (ly0+di)*HALO + (lx+dj);
            uint4 kk = *(const uint4*)(KB + pos*ROWDW + cg8*4);
            float k[8];
            k[0]=__uint_as_float(kk.x<<16); k[1]=__uint_as_float(kk.x&0xffff0000u);
            k[2]=__uint_as_float(kk.y<<16); k[3]=__uint_as_float(kk.y&0xffff0000u);
            k[4]=__uint_as_float(kk.z<<16); k[5]=__uint_as_float(kk.z&0xffff0000u);
            k[6]=__uint_as_float(kk.w<<16); k[7]=__uint_as_float(kk.w&0xffff0000u);
            if (di < 5) {
                float a = 0.f;
                #pragma unroll
                for (int c = 0; c < 8; ++c) a = fmaf(q0[c], k[c], a);
                p0[di*5+dj] = a;
            }
            if (di >= 1) {
                float a = 0.f;
                #pragma unroll
                for (int c = 0; c < 8; ++c) a = fmaf(q1[c], k[c], a);
                p1[(di-1)*5+dj] = a;
            }
        }
    }
    {   // self logits
        float s0 = 0.f, s1 = 0.f;
        #pragma unroll
        for (int c = 0; c < 8; ++c) { s0 = fmaf(q0[c],q0[c],s0); s1 = fmaf(q1[c],q1[c],s1); }
        p0[25] = s0; p1[25] = s1;
    }

    // ---- cross-lane reduce (8 channel-lanes), DPP only ----
    #pragma unroll
    for (int k = 0; k < 26; ++k) { p0[k] = reduce8(p0[k]); p1[k] = reduce8(p1[k]); }

    // ---- softmax (deferred normalization) ----
    float m0 = p0[0], m1 = p1[0];
    #pragma unroll
    for (int k = 1; k < 26; ++k) { m0 = fmaxf(m0,p0[k]); m1 = fmaxf(m1,p1[k]); }
    float s0 = 0.f, s1 = 0.f;
    #pragma unroll
    for (int k = 0; k < 26; ++k) {
        p0[k] = __expf(p0[k]-m0); s0 += p0[k];
        p1[k] = __expf(p1[k]-m1); s1 += p1[k];
    }
    const float rs0 = 1.f/s0, rs1 = 1.f/s1;

    // ---- aggregation from V buffer ----
    float o0[8], o1[8];
    #pragma unroll
    for (int c = 0; c < 8; ++c) { o0[c]=0.f; o1[c]=0.f; }
    const unsigned* VB = kv + KVDW;
    #pragma unroll
    for (int di = 0; di < 6; ++di) {
        #pragma unroll
        for (int dj = 0; dj < 5; ++dj) {
            const int pos = (ly0+di)*HALO + (lx+dj);
            uint4 vv = *(const uint4*)(VB + pos*ROWDW + cg8*4);
            float v[8];
            v[0]=__uint_as_float(vv.x<<16); v[1]=__uint_as_float(vv.x&0xffff0000u);
            v[2]=__uint_as_float(vv.y<<16); v[3]=__uint_as_float(vv.y&0xffff0000u);
            v[4]=__uint_as_float(vv.z<<16); v[5]=__uint_as_float(vv.z&0xffff0000u);
            v[6]=__uint_as_float(vv.w<<16); v[7]=__uint_as_float(vv.w&0xffff0000u);
            if (di < 5) {
                const float w = p0[di*5+dj];
                #pragma unroll
                for (int c = 0; c < 8; ++c) o0[c] = fmaf(w, v[c], o0[c]);
            }
            if (di >= 1) {
                const float w = p1[(di-1)*5+dj];
                #pragma unroll
                for (int c = 0; c < 8; ++c) o1[c] = fmaf(w, v[c], o1[c]);
            }
        }
    }
    {   // self slot (fp32 main_value, preloaded)
        float mv0[8] = {va0.x,va0.y,va0.z,va0.w,vb0.x,vb0.y,vb0.z,vb0.w};
        float mv1[8] = {va1.x,va1.y,va1.z,va1.w,vb1.x,vb1.y,vb1.z,vb1.w};
        #pragma unroll
        for (int c = 0; c < 8; ++c) {
            o0[c] = fmaf(p0[25], mv0[c], o0[c]);
            o1[c] = fmaf(p1[25], mv1[c], o1[c]);
        }
    }

    float4 r;
    r.x=o0[0]*rs0; r.y=o0[1]*rs0; r.z=o0[2]*rs0; r.w=o0[3]*rs0;
    *(float4*)(out+off0) = r;
    r.x=o0[4]*rs0; r.y=o0[5]*rs0; r.z=o0[6]*rs0; r.w=o0[7]*rs0;
    *(float4*)(out+off0+4) = r;
    r.x=o1[0]*rs1; r.y=o1[1]*rs1; r.z=o1[2]*rs1; r.w=o1[3]*rs1;
    *(float4*)(out+off1) = r;
    r.x=o1[4]*rs1; r.y=o1[5]*rs1; r.z=o1[6]*rs1; r.w=o1[7]*rs1;
    *(float4*)(out+off1+4) = r;
}

extern "C" void kernel_launch(void* const* d_in, const int* in_sizes, int n_in,
                              void* d_out, int out_size, void* d_ws, size_t ws_size,
                              hipStream_t stream) {
    const float* main_      = (const float*)d_in[0];
    const float* main_value = (const float*)d_in[1];
    const float* ref        = (const float*)d_in[2];
    const float* ref_value  = (const float*)d_in[3];
    float* out = (float*)d_out;

    local_attn_kernel<<<dim3(BATCH*16*16), dim3(256), 0, stream>>>(
        main_, main_value, ref, ref_value, out);
}

// Round 5
// 45.509 us; speedup vs baseline: 4.2047x; 4.2047x over previous
//
#include <hip/hip_runtime.h>

#define BATCH 4
#define HH 128
#define WW 128
#define CC 64
#define TH 8
#define TW 8
#define HALO 12
#define HPOS 144            // 12*12 halo positions
#define ROWDW 32            // 64 ch bf16 = 128 B = 32 dwords
#define KVDW (HPOS*ROWDW)   // dwords per buffer (4608)

__device__ __forceinline__ unsigned pack2bf(float a, float b){
  unsigned ua = __float_as_uint(a), ub = __float_as_uint(b);
  ua = (ua + 0x7fffu + ((ua>>16)&1u)) >> 16;            // RTN
  ub = (ub + 0x7fffu + ((ub>>16)&1u)) >> 16;
  return ua | (ub<<16);
}

template<int CTRL>
__device__ __forceinline__ float dpp_addstep(float x){
  int p = __builtin_amdgcn_update_dpp(0, __float_as_int(x), CTRL, 0xf, 0xf, true);
  return x + __int_as_float(p);
}
// sum across 8 consecutive lanes (groups aligned to lane&~7) — pure VALU/DPP
__device__ __forceinline__ float reduce8(float x){
  x = dpp_addstep<0xB1>(x);    // quad_perm [1,0,3,2] : xor 1
  x = dpp_addstep<0x4E>(x);    // quad_perm [2,3,0,1] : xor 2
  x = dpp_addstep<0x141>(x);   // row_half_mirror     : combine the two quads
  return x;
}

__global__ __launch_bounds__(256, 2) void local_attn_kernel(
    const float* __restrict__ main_,
    const float* __restrict__ main_value,
    const float* __restrict__ ref,
    const float* __restrict__ ref_value,
    float* __restrict__ out)
{
    __shared__ unsigned kv[2*KVDW];     // K halo then V halo, bf16x2, 36864 B

    const int t   = threadIdx.x;
    const int nwg = BATCH*16*16;        // 1024, divisible by 8 -> bijective swizzle
    const int blk = (blockIdx.x & 7) * (nwg>>3) + (blockIdx.x >> 3);
    const int bx  = blk & 15;
    const int by  = (blk>>4) & 15;
    const int b   = blk >> 8;

    const int lane = t & 63;
    const int wave = t >> 6;
    const int cg8  = lane & 7;          // channel slot: ch [cg8*8, cg8*8+8)
    const int lx   = lane >> 3;         // 0..7 tile column
    const int ly0  = wave*2;            // this thread owns pixels (ly0,lx) and (ly0+1,lx)

    const int gx  = bx*TW + lx;
    const int gy0 = by*TH + ly0;

    const size_t img  = (size_t)b*HH*WW*CC;
    const size_t off0 = img + ((size_t)gy0*WW + gx)*CC + cg8*8;
    const size_t off1 = off0 + (size_t)WW*CC;

    // ---- q loads first (latency hides under staging) ----
    float4 qa0 = *(const float4*)(main_+off0), qb0 = *(const float4*)(main_+off0+4);
    float4 qa1 = *(const float4*)(main_+off1), qb1 = *(const float4*)(main_+off1+4);

    const int y0 = by*TH - 2, x0 = bx*TW - 2;

    // ---- stage K and V halos as bf16 (zero-fill OOB) ----
    #pragma unroll
    for (int half = 0; half < 2; ++half) {
        const float* src = half ? ref_value : ref;
        unsigned* dst = kv + half*KVDW;
        #pragma unroll
        for (int it = 0; it < 5; ++it) {
            int u = t + (it<<8);
            if (u < HPOS*8) {
                int pos = u >> 3, c8 = u & 7;
                int hy = pos/12, hx = pos - hy*12;
                int yy = y0+hy, xx = x0+hx;
                float4 a = make_float4(0.f,0.f,0.f,0.f);
                float4 c = make_float4(0.f,0.f,0.f,0.f);
                if ((unsigned)yy < HH && (unsigned)xx < WW) {
                    const float* g = src + img + ((size_t)yy*WW+xx)*CC + c8*8;
                    a = ((const float4*)g)[0];
                    c = ((const float4*)g)[1];
                }
                uint4 w;
                w.x = pack2bf(a.x,a.y); w.y = pack2bf(a.z,a.w);
                w.z = pack2bf(c.x,c.y); w.w = pack2bf(c.z,c.w);
                *(uint4*)(dst + pos*ROWDW + c8*4) = w;
            }
        }
    }

    __syncthreads();    // the ONLY barrier

    float q0[8] = {qa0.x,qa0.y,qa0.z,qa0.w,qb0.x,qb0.y,qb0.z,qb0.w};
    float q1[8] = {qa1.x,qa1.y,qa1.z,qa1.w,qb1.x,qb1.y,qb1.z,qb1.w};

    // ---- logits: 6 halo rows x 5 cols serve both pixels ----
    float p0[26], p1[26];
    const unsigned* KB = kv;
    #pragma unroll
    for (int di = 0; di < 6; ++di) {
        #pragma unroll
        for (int dj = 0; dj < 5; ++dj) {
            const int pos = (ly0+di)*HALO + (lx+dj);
            uint4 kk = *(const uint4*)(KB + pos*ROWDW + cg8*4);
            float k[8];
            k[0]=__uint_as_float(kk.x<<16); k[1]=__uint_as_float(kk.x&0xffff0000u);
            k[2]=__uint_as_float(kk.y<<16); k[3]=__uint_as_float(kk.y&0xffff0000u);
            k[4]=__uint_as_float(kk.z<<16); k[5]=__uint_as_float(kk.z&0xffff0000u);
            k[6]=__uint_as_float(kk.w<<16); k[7]=__uint_as_float(kk.w&0xffff0000u);
            if (di < 5) {
                float a = 0.f;
                #pragma unroll
                for (int c = 0; c < 8; ++c) a = fmaf(q0[c], k[c], a);
                p0[di*5+dj] = a;
            }
            if (di >= 1) {
                float a = 0.f;
                #pragma unroll
                for (int c = 0; c < 8; ++c) a = fmaf(q1[c], k[c], a);
                p1[(di-1)*5+dj] = a;
            }
        }
    }
    {   // self logits
        float s0 = 0.f, s1 = 0.f;
        #pragma unroll
        for (int c = 0; c < 8; ++c) { s0 = fmaf(q0[c],q0[c],s0); s1 = fmaf(q1[c],q1[c],s1); }
        p0[25] = s0; p1[25] = s1;
    }

    // ---- cross-lane reduce (8 channel-lanes), DPP only ----
    #pragma unroll
    for (int k = 0; k < 26; ++k) { p0[k] = reduce8(p0[k]); p1[k] = reduce8(p1[k]); }

    // ---- softmax (deferred normalization) ----
    float m0 = p0[0], m1 = p1[0];
    #pragma unroll
    for (int k = 1; k < 26; ++k) { m0 = fmaxf(m0,p0[k]); m1 = fmaxf(m1,p1[k]); }
    float s0 = 0.f, s1 = 0.f;
    #pragma unroll
    for (int k = 0; k < 26; ++k) {
        p0[k] = __expf(p0[k]-m0); s0 += p0[k];
        p1[k] = __expf(p1[k]-m1); s1 += p1[k];
    }
    const float rs0 = 1.f/s0, rs1 = 1.f/s1;

    // ---- self-value loads issued HERE: ~30 LDS iterations hide their latency,
    //      and their 16 VGPRs are not live across logits/softmax ----
    float4 va0 = *(const float4*)(main_value+off0), vb0 = *(const float4*)(main_value+off0+4);
    float4 va1 = *(const float4*)(main_value+off1), vb1 = *(const float4*)(main_value+off1+4);

    // ---- aggregation from V buffer ----
    float o0[8], o1[8];
    #pragma unroll
    for (int c = 0; c < 8; ++c) { o0[c]=0.f; o1[c]=0.f; }
    const unsigned* VB = kv + KVDW;
    #pragma unroll
    for (int di = 0; di < 6; ++di) {
        #pragma unroll
        for (int dj = 0; dj < 5; ++dj) {
            const int pos = (ly0+di)*HALO + (lx+dj);
            uint4 vv = *(const uint4*)(VB + pos*ROWDW + cg8*4);
            float v[8];
            v[0]=__uint_as_float(vv.x<<16); v[1]=__uint_as_float(vv.x&0xffff0000u);
            v[2]=__uint_as_float(vv.y<<16); v[3]=__uint_as_float(vv.y&0xffff0000u);
            v[4]=__uint_as_float(vv.z<<16); v[5]=__uint_as_float(vv.z&0xffff0000u);
            v[6]=__uint_as_float(vv.w<<16); v[7]=__uint_as_float(vv.w&0xffff0000u);
            if (di < 5) {
                const float w = p0[di*5+dj];
                #pragma unroll
                for (int c = 0; c < 8; ++c) o0[c] = fmaf(w, v[c], o0[c]);
            }
            if (di >= 1) {
                const float w = p1[(di-1)*5+dj];
                #pragma unroll
                for (int c = 0; c < 8; ++c) o1[c] = fmaf(w, v[c], o1[c]);
            }
        }
    }
    {   // self slot (fp32 main_value, preloaded)
        float mv0[8] = {va0.x,va0.y,va0.z,va0.w,vb0.x,vb0.y,vb0.z,vb0.w};
        float mv1[8] = {va1.x,va1.y,va1.z,va1.w,vb1.x,vb1.y,vb1.z,vb1.w};
        #pragma unroll
        for (int c = 0; c < 8; ++c) {
            o0[c] = fmaf(p0[25], mv0[c], o0[c]);
            o1[c] = fmaf(p1[25], mv1[c], o1[c]);
        }
    }

    float4 r;
    r.x=o0[0]*rs0; r.y=o0[1]*rs0; r.z=o0[2]*rs0; r.w=o0[3]*rs0;
    *(float4*)(out+off0) = r;
    r.x=o0[4]*rs0; r.y=o0[5]*rs0; r.z=o0[6]*rs0; r.w=o0[7]*rs0;
    *(float4*)(out+off0+4) = r;
    r.x=o1[0]*rs1; r.y=o1[1]*rs1; r.z=o1[2]*rs1; r.w=o1[3]*rs1;
    *(float4*)(out+off1) = r;
    r.x=o1[4]*rs1; r.y=o1[5]*rs1; r.z=o1[6]*rs1; r.w=o1[7]*rs1;
    *(float4*)(out+off1+4) = r;
}

extern "C" void kernel_launch(void* const* d_in, const int* in_sizes, int n_in,
                              void* d_out, int out_size, void* d_ws, size_t ws_size,
                              hipStream_t stream) {
    const float* main_      = (const float*)d_in[0];
    const float* main_value = (const float*)d_in[1];
    const float* ref        = (const float*)d_in[2];
    const float* ref_value  = (const float*)d_in[3];
    float* out = (float*)d_out;

    local_attn_kernel<<<dim3(BATCH*16*16), dim3(256), 0, stream>>>(
        main_, main_value, ref, ref_value, out);
}

// Round 6
// 31.428 us; speedup vs baseline: 6.0886x; 1.4481x over previous
//
#include <hip/hip_runtime.h>

#define BATCH 4
#define HH 128
#define WW 128
#define CC 64
#define TH 8
#define TW 8
#define HALO 12
#define HPOS 144            // 12*12 halo positions
#define ROWDW 32            // 64 ch bf16 = 128 B = 32 dwords
#define KVDW (HPOS*ROWDW)   // dwords per buffer (4608)

__device__ __forceinline__ unsigned pack2bf(float a, float b){
  unsigned ua = __float_as_uint(a), ub = __float_as_uint(b);
  ua = (ua + 0x7fffu + ((ua>>16)&1u)) >> 16;            // RTN
  ub = (ub + 0x7fffu + ((ub>>16)&1u)) >> 16;
  return ua | (ub<<16);
}

__device__ __forceinline__ void unpack8(uint4 u, float* f){
  f[0]=__uint_as_float(u.x<<16); f[1]=__uint_as_float(u.x&0xffff0000u);
  f[2]=__uint_as_float(u.y<<16); f[3]=__uint_as_float(u.y&0xffff0000u);
  f[4]=__uint_as_float(u.z<<16); f[5]=__uint_as_float(u.z&0xffff0000u);
  f[6]=__uint_as_float(u.w<<16); f[7]=__uint_as_float(u.w&0xffff0000u);
}

template<int CTRL>
__device__ __forceinline__ float dpp_addstep(float x){
  int p = __builtin_amdgcn_update_dpp(0, __float_as_int(x), CTRL, 0xf, 0xf, true);
  return x + __int_as_float(p);
}
// sum across 8 consecutive lanes (groups aligned to lane&~7) — pure VALU/DPP
__device__ __forceinline__ float reduce8(float x){
  x = dpp_addstep<0xB1>(x);    // quad_perm [1,0,3,2] : xor 1
  x = dpp_addstep<0x4E>(x);    // quad_perm [2,3,0,1] : xor 2
  x = dpp_addstep<0x141>(x);   // row_half_mirror     : combine the two quads
  return x;
}

__global__ __launch_bounds__(256, 2) void local_attn_kernel(
    const float* __restrict__ main_,
    const float* __restrict__ main_value,
    const float* __restrict__ ref,
    const float* __restrict__ ref_value,
    float* __restrict__ out)
{
    __shared__ unsigned kv[2*KVDW];     // K halo then V halo, bf16x2, 36864 B

    const int t   = threadIdx.x;
    const int nwg = BATCH*16*16;        // 1024, divisible by 8 -> bijective swizzle
    const int blk = (blockIdx.x & 7) * (nwg>>3) + (blockIdx.x >> 3);
    const int bx  = blk & 15;
    const int by  = (blk>>4) & 15;
    const int b   = blk >> 8;

    const int lane = t & 63;
    const int wave = t >> 6;
    const int cg8  = lane & 7;          // channel slot: ch [cg8*8, cg8*8+8)
    const int lx   = lane >> 3;         // 0..7 tile column
    const int ly0  = wave*2;            // this thread owns pixels (ly0,lx) and (ly0+1,lx)

    const int gx  = bx*TW + lx;
    const int gy0 = by*TH + ly0;

    const size_t img  = (size_t)b*HH*WW*CC;
    const size_t off0 = img + ((size_t)gy0*WW + gx)*CC + cg8*8;
    const size_t off1 = off0 + (size_t)WW*CC;

    // ---- q loads first (latency hides under staging) ----
    float4 qa0 = *(const float4*)(main_+off0), qb0 = *(const float4*)(main_+off0+4);
    float4 qa1 = *(const float4*)(main_+off1), qb1 = *(const float4*)(main_+off1+4);

    const int y0 = by*TH - 2, x0 = bx*TW - 2;

    // ---- stage K and V halos as bf16 (zero-fill OOB) ----
    #pragma unroll
    for (int half = 0; half < 2; ++half) {
        const float* src = half ? ref_value : ref;
        unsigned* dst = kv + half*KVDW;
        #pragma unroll
        for (int it = 0; it < 5; ++it) {
            int u = t + (it<<8);
            if (u < HPOS*8) {
                int pos = u >> 3, c8 = u & 7;
                int hy = pos/12, hx = pos - hy*12;
                int yy = y0+hy, xx = x0+hx;
                float4 a = make_float4(0.f,0.f,0.f,0.f);
                float4 c = make_float4(0.f,0.f,0.f,0.f);
                if ((unsigned)yy < HH && (unsigned)xx < WW) {
                    const float* g = src + img + ((size_t)yy*WW+xx)*CC + c8*8;
                    a = ((const float4*)g)[0];
                    c = ((const float4*)g)[1];
                }
                uint4 w;
                w.x = pack2bf(a.x,a.y); w.y = pack2bf(a.z,a.w);
                w.z = pack2bf(c.x,c.y); w.w = pack2bf(c.z,c.w);
                *(uint4*)(dst + pos*ROWDW + c8*4) = w;
            }
        }
    }

    __syncthreads();    // the ONLY barrier

    // ---- self-value loads: land while the online loop runs ----
    float4 va0 = *(const float4*)(main_value+off0), vb0 = *(const float4*)(main_value+off0+4);
    float4 va1 = *(const float4*)(main_value+off1), vb1 = *(const float4*)(main_value+off1+4);

    float q0[8] = {qa0.x,qa0.y,qa0.z,qa0.w,qb0.x,qb0.y,qb0.z,qb0.w};
    float q1[8] = {qa1.x,qa1.y,qa1.z,qa1.w,qb1.x,qb1.y,qb1.z,qb1.w};

    // ---- fused online-softmax pass: logit -> weight -> accumulate ----
    float o0[8], o1[8];
    #pragma unroll
    for (int c = 0; c < 8; ++c) { o0[c]=0.f; o1[c]=0.f; }
    float m0 = -INFINITY, m1 = -INFINITY, s0 = 0.f, s1 = 0.f;

    const unsigned* KB = kv;
    const unsigned* VB = kv + KVDW;

    #pragma unroll
    for (int di = 0; di < 6; ++di) {
        #pragma unroll
        for (int dj = 0; dj < 5; ++dj) {
            const int pos = (ly0+di)*HALO + (lx+dj);
            uint4 kk = *(const uint4*)(KB + pos*ROWDW + cg8*4);
            uint4 vv = *(const uint4*)(VB + pos*ROWDW + cg8*4);
            float k[8], v[8];
            unpack8(kk, k);
            unpack8(vv, v);
            if (di < 5) {                     // pixel 0 uses halo rows 0..4
                float l = 0.f;
                #pragma unroll
                for (int c = 0; c < 8; ++c) l = fmaf(q0[c], k[c], l);
                l = reduce8(l);
                float mn = fmaxf(m0, l);
                float corr = __expf(m0 - mn);
                float w    = __expf(l  - mn);
                s0 = fmaf(s0, corr, w);
                #pragma unroll
                for (int c = 0; c < 8; ++c) o0[c] = fmaf(o0[c], corr, w * v[c]);
                m0 = mn;
            }
            if (di >= 1) {                    // pixel 1 uses halo rows 1..5
                float l = 0.f;
                #pragma unroll
                for (int c = 0; c < 8; ++c) l = fmaf(q1[c], k[c], l);
                l = reduce8(l);
                float mn = fmaxf(m1, l);
                float corr = __expf(m1 - mn);
                float w    = __expf(l  - mn);
                s1 = fmaf(s1, corr, w);
                #pragma unroll
                for (int c = 0; c < 8; ++c) o1[c] = fmaf(o1[c], corr, w * v[c]);
                m1 = mn;
            }
        }
    }

    // ---- self slot: fp32 q.q logit, fp32 main_value ----
    {
        float mv0[8] = {va0.x,va0.y,va0.z,va0.w,vb0.x,vb0.y,vb0.z,vb0.w};
        float mv1[8] = {va1.x,va1.y,va1.z,va1.w,vb1.x,vb1.y,vb1.z,vb1.w};
        float l0 = 0.f, l1 = 0.f;
        #pragma unroll
        for (int c = 0; c < 8; ++c) { l0 = fmaf(q0[c],q0[c],l0); l1 = fmaf(q1[c],q1[c],l1); }
        l0 = reduce8(l0); l1 = reduce8(l1);
        float mn0 = fmaxf(m0, l0), corr0 = __expf(m0-mn0), w0 = __expf(l0-mn0);
        float mn1 = fmaxf(m1, l1), corr1 = __expf(m1-mn1), w1 = __expf(l1-mn1);
        s0 = fmaf(s0, corr0, w0);
        s1 = fmaf(s1, corr1, w1);
        #pragma unroll
        for (int c = 0; c < 8; ++c) {
            o0[c] = fmaf(o0[c], corr0, w0 * mv0[c]);
            o1[c] = fmaf(o1[c], corr1, w1 * mv1[c]);
        }
    }

    const float rs0 = 1.f/s0, rs1 = 1.f/s1;

    float4 r;
    r.x=o0[0]*rs0; r.y=o0[1]*rs0; r.z=o0[2]*rs0; r.w=o0[3]*rs0;
    *(float4*)(out+off0) = r;
    r.x=o0[4]*rs0; r.y=o0[5]*rs0; r.z=o0[6]*rs0; r.w=o0[7]*rs0;
    *(float4*)(out+off0+4) = r;
    r.x=o1[0]*rs1; r.y=o1[1]*rs1; r.z=o1[2]*rs1; r.w=o1[3]*rs1;
    *(float4*)(out+off1) = r;
    r.x=o1[4]*rs1; r.y=o1[5]*rs1; r.z=o1[6]*rs1; r.w=o1[7]*rs1;
    *(float4*)(out+off1+4) = r;
}

extern "C" void kernel_launch(void* const* d_in, const int* in_sizes, int n_in,
                              void* d_out, int out_size, void* d_ws, size_t ws_size,
                              hipStream_t stream) {
    const float* main_      = (const float*)d_in[0];
    const float* main_value = (const float*)d_in[1];
    const float* ref        = (const float*)d_in[2];
    const float* ref_value  = (const float*)d_in[3];
    float* out = (float*)d_out;

    local_attn_kernel<<<dim3(BATCH*16*16), dim3(256), 0, stream>>>(
        main_, main_value, ref, ref_value, out);
}

// Round 8
// 31.142 us; speedup vs baseline: 6.1444x; 1.0092x over previous
//
#include <hip/hip_runtime.h>

#define HH 128
#define WW 128
#define CC 64
#define IMG (HH*WW*CC)

__device__ __forceinline__ unsigned pack2bf(float a, float b){
  unsigned ua = __float_as_uint(a), ub = __float_as_uint(b);
  ua = (ua + 0x7fffu + ((ua>>16)&1u)) >> 16;            // RTN
  ub = (ub + 0x7fffu + ((ub>>16)&1u)) >> 16;
  return ua | (ub<<16);
}

__device__ __forceinline__ void unpack8(uint4 u, float* f){
  f[0]=__uint_as_float(u.x<<16); f[1]=__uint_as_float(u.x&0xffff0000u);
  f[2]=__uint_as_float(u.y<<16); f[3]=__uint_as_float(u.y&0xffff0000u);
  f[4]=__uint_as_float(u.z<<16); f[5]=__uint_as_float(u.z&0xffff0000u);
  f[6]=__uint_as_float(u.w<<16); f[7]=__uint_as_float(u.w&0xffff0000u);
}

template<int CTRL>
__device__ __forceinline__ float dpp_addstep(float x){
  int p = __builtin_amdgcn_update_dpp(0, __float_as_int(x), CTRL, 0xf, 0xf, true);
  return x + __int_as_float(p);
}
// sum across 8 consecutive lanes (groups aligned to lane&~7) — pure VALU/DPP
__device__ __forceinline__ float reduce8(float x){
  x = dpp_addstep<0xB1>(x);    // xor 1
  x = dpp_addstep<0x4E>(x);    // xor 2
  x = dpp_addstep<0x141>(x);   // row_half_mirror
  return x;
}

// stage(st): global fp32 -> regs (zero-fill OOB), later packed bf16 -> LDS.
// unit A = thread t      : covers K pos 0..23 (t<192) and V pos 0..7 (t>=192)
// unit B = thread t<128  : covers V pos 8..23
#define STAGE_LOAD(st, A0,A1,B0,B1) {                                          \
  A0=A1=B0=B1=make_float4(0.f,0.f,0.f,0.f);                                    \
  int yya = y0 + 2*(st) + prA;                                                 \
  if (vxA && (unsigned)yya < HH) {                                             \
    const float* g = srcA + ((size_t)yya*WW + xxA)*CC + c8s*8;                 \
    A0 = ((const float4*)g)[0]; A1 = ((const float4*)g)[1];                    \
  }                                                                            \
  int yyb = y0 + 2*(st) + prB;                                                 \
  if (hasB && vxB && (unsigned)yyb < HH) {                                     \
    const float* g = srcB + ((size_t)yyb*WW + xxB)*CC + c8s*8;                 \
    B0 = ((const float4*)g)[0]; B1 = ((const float4*)g)[1];                    \
  } }

#define STAGE_WRITE(bb, A0,A1,B0,B1) {                                         \
  kv4[(bb)*384 + dstA] = make_uint4(pack2bf(A0.x,A0.y),pack2bf(A0.z,A0.w),     \
                                    pack2bf(A1.x,A1.y),pack2bf(A1.z,A1.w));    \
  if (hasB)                                                                    \
    kv4[(bb)*384 + dstB] = make_uint4(pack2bf(B0.x,B0.y),pack2bf(B0.z,B0.w),   \
                                      pack2bf(B1.x,B1.y),pack2bf(B1.z,B1.w));  \
  }

__global__ __launch_bounds__(256, 2) void local_attn_kernel(
    const float* __restrict__ main_,
    const float* __restrict__ main_value,
    const float* __restrict__ ref,
    const float* __restrict__ ref_value,
    float* __restrict__ out)
{
    // [buf(2)][mat(2)][pos(24)][slot(8)] uint4 = 12288 B
    __shared__ uint4 kv4[2*384];

    const int t   = threadIdx.x;
    const int blk = (blockIdx.x & 7) * 128 + (blockIdx.x >> 3);  // XCD swizzle (1024%8==0)
    const int bx  = blk & 15;
    const int by  = (blk >> 4) & 15;
    const int b   = blk >> 8;

    const int lane = t & 63;
    const int wv   = t >> 6;        // 0..3
    const int cg8  = lane & 7;      // channel slot (8 ch each)
    const int lx   = lane >> 3;     // 0..7 tile column
    const int pya  = wv;            // pixel A tile-row; pixel B = wv+4 (wave balance)

    const int gx = bx*8 + lx;
    const size_t img  = (size_t)b * IMG;
    const size_t offA = img + ((size_t)(by*8 + pya)*WW + gx)*CC + cg8*8;
    const size_t offB = offA + (size_t)4*WW*CC;

    const int y0 = by*8 - 2, x0 = bx*8 - 2;

    // ---- q loads first (latency hides under first staging) ----
    float4 qa0 = *(const float4*)(main_+offA), qa1 = *(const float4*)(main_+offA+4);
    float4 qb0 = *(const float4*)(main_+offB), qb1 = *(const float4*)(main_+offB+4);

    // ---- staging descriptors (fixed per thread; row advances 2/step) ----
    const int   mA  = (t >= 192);
    const int   rA  = t - 192*mA;
    const int   posA= rA >> 3;
    const int   c8s = t & 7;
    const int   prA = (posA >= 12);
    const int   pcA = posA - 12*prA;
    const int   xxA = x0 + pcA;
    const bool  vxA = (unsigned)xxA < WW;
    const float* srcA = (mA ? ref_value : ref) + img;
    const int   dstA = mA*192 + posA*8 + (c8s ^ (posA & 7));

    const bool  hasB = (t < 128);
    const int   posB = 8 + (t >> 3);
    const int   prB  = (posB >= 12);
    const int   pcB  = posB - 12*prB;
    const int   xxB  = x0 + pcB;
    const bool  vxB  = (unsigned)xxB < WW;
    const float* srcB = ref_value + img;
    const int   dstB = 192 + posB*8 + (c8s ^ (posB & 7));

    // ---- prologue: stage step 0 ----
    {
        float4 A0,A1,B0,B1;
        STAGE_LOAD(0, A0,A1,B0,B1);
        STAGE_WRITE(0, A0,A1,B0,B1);
    }
    __syncthreads();

    float qA[8] = {qa0.x,qa0.y,qa0.z,qa0.w,qa1.x,qa1.y,qa1.z,qa1.w};
    float qB[8] = {qb0.x,qb0.y,qb0.z,qb0.w,qb1.x,qb1.y,qb1.z,qb1.w};

    // ---- per-pixel softmax shift = self logit |q|^2 (exact, overflow-safe) ----
    float lqA, lqB;
    {
        float a = 0.f, b2 = 0.f;
        #pragma unroll
        for (int c = 0; c < 8; ++c) { a = fmaf(qA[c],qA[c],a); b2 = fmaf(qB[c],qB[c],b2); }
        lqA = reduce8(a); lqB = reduce8(b2);
    }

    float oA[8], oB[8];
    #pragma unroll
    for (int c = 0; c < 8; ++c) { oA[c]=0.f; oB[c]=0.f; }
    float sA = 0.f, sB = 0.f;

    // ---- streamed K/V: 6 steps x 2 halo rows, double-buffered ----
    #pragma unroll
    for (int s = 0; s < 6; ++s) {
        float4 nA0,nA1,nB0,nB1;
        if (s < 5) STAGE_LOAD(s+1, nA0,nA1,nB0,nB1);

        const int bb = s & 1;
        #pragma unroll
        for (int rl = 0; rl < 2; ++rl) {
            const int row = 2*s + rl;                       // halo row 0..11
            if (row >= pya && row <= pya+8) {               // wave-uniform gate
                const bool actA = (row <= pya+4);
                const bool actB = (row >= pya+4);
                #pragma unroll
                for (int dj = 0; dj < 5; ++dj) {
                    const int pl  = rl*12 + lx + dj;
                    const int sw  = cg8 ^ (pl & 7);
                    const uint4 kk = kv4[bb*384 +       pl*8 + sw];
                    const uint4 vv = kv4[bb*384 + 192 + pl*8 + sw];
                    float k8[8], v8[8];
                    unpack8(kk, k8);
                    unpack8(vv, v8);
                    if (actA) {
                        float l = 0.f;
                        #pragma unroll
                        for (int c = 0; c < 8; ++c) l = fmaf(qA[c], k8[c], l);
                        l = reduce8(l);
                        float w = __expf(l - lqA);          // arg <= ~45: safe
                        sA += w;
                        #pragma unroll
                        for (int c = 0; c < 8; ++c) oA[c] = fmaf(w, v8[c], oA[c]);
                    }
                    if (actB) {
                        float l = 0.f;
                        #pragma unroll
                        for (int c = 0; c < 8; ++c) l = fmaf(qB[c], k8[c], l);
                        l = reduce8(l);
                        float w = __expf(l - lqB);
                        sB += w;
                        #pragma unroll
                        for (int c = 0; c < 8; ++c) oB[c] = fmaf(w, v8[c], oB[c]);
                    }
                }
            }
        }

        if (s < 5) {
            STAGE_WRITE(bb^1, nA0,nA1,nB0,nB1);
            __syncthreads();
        }
    }

    // ---- self slot: weight is exactly exp(lq - lq) = 1 ----
    {
        float4 va0 = *(const float4*)(main_value+offA), va1 = *(const float4*)(main_value+offA+4);
        float4 vb0 = *(const float4*)(main_value+offB), vb1 = *(const float4*)(main_value+offB+4);
        float mvA[8] = {va0.x,va0.y,va0.z,va0.w,va1.x,va1.y,va1.z,va1.w};
        float mvB[8] = {vb0.x,vb0.y,vb0.z,vb0.w,vb1.x,vb1.y,vb1.z,vb1.w};
        sA += 1.f; sB += 1.f;
        #pragma unroll
        for (int c = 0; c < 8; ++c) {
            oA[c] += mvA[c];
            oB[c] += mvB[c];
        }
    }

    const float rsA = 1.f/sA, rsB = 1.f/sB;
    float4 r;
    r.x=oA[0]*rsA; r.y=oA[1]*rsA; r.z=oA[2]*rsA; r.w=oA[3]*rsA;
    *(float4*)(out+offA) = r;
    r.x=oA[4]*rsA; r.y=oA[5]*rsA; r.z=oA[6]*rsA; r.w=oA[7]*rsA;
    *(float4*)(out+offA+4) = r;
    r.x=oB[0]*rsB; r.y=oB[1]*rsB; r.z=oB[2]*rsB; r.w=oB[3]*rsB;
    *(float4*)(out+offB) = r;
    r.x=oB[4]*rsB; r.y=oB[5]*rsB; r.z=oB[6]*rsB; r.w=oB[7]*rsB;
    *(float4*)(out+offB+4) = r;
}

extern "C" void kernel_launch(void* const* d_in, const int* in_sizes, int n_in,
                              void* d_out, int out_size, void* d_ws, size_t ws_size,
                              hipStream_t stream) {
    const float* main_      = (const float*)d_in[0];
    const float* main_value = (const float*)d_in[1];
    const float* ref        = (const float*)d_in[2];
    const float* ref_value  = (const float*)d_in[3];
    float* out = (float*)d_out;

    local_attn_kernel<<<dim3(4*16*16), dim3(256), 0, stream>>>(
        main_, main_value, ref, ref_value, out);
}